// Round 5
// baseline (5500.873 us; speedup 1.0000x reference)
//
#include <hip/hip_runtime.h>
#include <hip/hip_bf16.h>

#define Hd 512
#define Bd 512
#define Vd 128
#define Sd 256

typedef _Float16 half8 __attribute__((ext_vector_type(8)));
typedef float float4v __attribute__((ext_vector_type(4)));

__device__ __forceinline__ float sigf(float v) { return 1.0f / (1.0f + __expf(-v)); }
__device__ __forceinline__ float tanhfast(float v) { return 1.0f - 2.0f / (__expf(2.0f * v) + 1.0f); }

// ---------------- prep kernels (layouts identical to R3/R4) ----------------
__global__ __launch_bounds__(256) void prep_wxt(
    const float* __restrict__ WxF, const float* __restrict__ bxF, const float* __restrict__ bhF,
    const float* __restrict__ WxB, const float* __restrict__ bxB, const float* __restrict__ bhB,
    float* __restrict__ wxt) {
  int e = blockIdx.x * 256 + threadIdx.x;
  int n = e & 2047;
  int v = (e >> 11) & 127;
  int dir = e >> 18;
  int k = n >> 2, g = n & 3;
  const float* Wx = dir ? WxB : WxF;
  const float* bx = dir ? bxB : bxF;
  const float* bh = dir ? bhB : bhF;
  int gk = g * Hd + k;
  wxt[e] = Wx[gk * Vd + v] + bx[gk] + bh[gk];
}

__global__ __launch_bounds__(256) void prep_wh16(
    const float* __restrict__ WhF, const float* __restrict__ WhB, _Float16* __restrict__ whr) {
  int e = blockIdx.x * 256 + threadIdx.x;
  int hc = e & 511;
  int n = (e >> 9) & 2047;
  int dir = e >> 20;
  int k = n >> 2, g = n & 3;
  const float* Wh = dir ? WhB : WhF;
  whr[e] = (_Float16)Wh[(g * Hd + k) * Hd + hc];
}

__global__ __launch_bounds__(256) void prep_wfc16(
    const float* __restrict__ Wfc, _Float16* __restrict__ wfc16) {
  int e = blockIdx.x * 256 + threadIdx.x;
  int hc = e & 511;
  int v = (e >> 9) & 127;
  int dir = e >> 16;
  wfc16[e] = (_Float16)Wfc[v * 1024 + dir * 512 + hc];
}

__global__ __launch_bounds__(256) void init_zero(float* __restrict__ p, int n4) {
  int e = blockIdx.x * 256 + threadIdx.x;
  if (e < n4) {
    float4 z; z.x = 0.f; z.y = 0.f; z.z = 0.f; z.w = 0.f;
    ((float4*)p)[e] = z;
  }
}

__global__ __launch_bounds__(256) void init_out(const float* __restrict__ bfc,
                                                float* __restrict__ out) {
  int e = blockIdx.x * 256 + threadIdx.x;
  int v0 = (e & 31) * 4;
  ((float4*)out)[e] = *(const float4*)&bfc[v0];
}

// ---------------- persistent BiLSTM kernel ----------------
// 136 blocks x 256 thr, 1 block/CU (143 KB LDS). grp = bid & 7 -> all 17 blocks of a
// group land on ONE XCD (round-robin heuristic; correctness holds regardless).
// role = bid >> 3: 0..15 = LSTM nt tile, 16 = FC. dir = grp>>2, mt = grp&3.
// Sync: flags[grp][nt] = highest h iteration published for that 32-k slice (monotone).
// Ring: 3 slots. lstm_rdone[grp] (16/iter) + fc_rdone[grp] (1/iter) guard slot reuse.
#define BTP 520
__global__ __launch_bounds__(256, 1) void bilstm_persist(
    const float* __restrict__ wxt, const int* __restrict__ x,
    const _Float16* __restrict__ whr, const _Float16* __restrict__ wfc16,
    _Float16* __restrict__ hring, int* __restrict__ cnt, float* __restrict__ out) {
  __shared__ _Float16 Bt[128 * BTP];   // 133,120 B weight tile, resident all 256 iters
  __shared__ _Float16 hT[128 * 40];    // 10,240 B h transpose staging

  const int tid = threadIdx.x;
  const int lane = tid & 63;
  const int w = tid >> 6;
  const int bid = blockIdx.x;
  const int grp = bid & 7;
  const int role = bid >> 3;           // 0..16
  const bool isFC = (role == 16);
  const int dir = grp >> 2;
  const int mt = grp & 3;
  const int nt = isFC ? 0 : role;
  const int b0 = mt * 128;

  int* flags = cnt + grp * 16;         // [nt]
  int* lrd = cnt + 128 + grp;          // lstm read-done counter
  int* frd = cnt + 136 + grp;          // fc read-done counter

  const _Float16* Bsrc = isFC ? (wfc16 + dir * (128 * 512))
                              : (whr + ((size_t)(dir * 2048 + nt * 128)) * 512);

  // stage weight tile into padded LDS (once)
  for (int e = tid; e < 128 * 64; e += 256) {
    int row = e >> 6, seg = e & 63;
    *(half8*)&Bt[row * BTP + seg * 8] = *(const half8*)&Bsrc[row * 512 + seg * 8];
  }
  __syncthreads();

  const int wn0 = (w & 1) * 64;
  const int wb0 = (w >> 1) * 64;
  int aoff[4], boff[4];
#pragma unroll
  for (int i = 0; i < 4; ++i) {
    aoff[i] = (b0 + wb0 + i * 16 + (lane & 15)) * 512 + (lane >> 4) * 8;
    boff[i] = (wn0 + i * 16 + (lane & 15)) * BTP + (lane >> 4) * 8;
  }
  const int klq = (wn0 >> 2) + (lane >> 4);

  float creg[4][4];
#pragma unroll
  for (int mi = 0; mi < 4; ++mi)
#pragma unroll
    for (int ni = 0; ni < 4; ++ni) creg[mi][ni] = 0.f;

  for (int it = 0; it < 256; ++it) {
    const int tcur = dir ? (255 - it) : it;
    const _Float16* hsrc = hring + (size_t)((isFC ? (it + 1) : it) % 3) * 524288 + dir * 262144;
    _Float16* hdst = hring + (size_t)((it + 1) % 3) * 524288 + dir * 262144;

    // ---- static-data prefetch BEFORE the wait (overlaps publish latency) ----
    float4 wpre[4][4];
    if (!isFC) {
      int xv[4];
#pragma unroll
      for (int mi = 0; mi < 4; ++mi)
        xv[mi] = x[(b0 + wb0 + mi * 16 + (lane & 15)) * Sd + tcur];
#pragma unroll
      for (int mi = 0; mi < 4; ++mi)
#pragma unroll
        for (int ni = 0; ni < 4; ++ni)
          wpre[mi][ni] = *(const float4*)&wxt[(size_t)(dir * Vd + xv[mi]) * 2048 +
                                              (nt * 32 + klq + ni * 4) * 4];
    }

    // ---- wave-autonomous readiness: all 16 slices of the needed h published ----
    const int need = isFC ? (it + 1) : it;
    if (need > 0) {
      for (;;) {
        int f = need;
        if (lane < 16) f = __hip_atomic_load(&flags[lane], __ATOMIC_RELAXED, __HIP_MEMORY_SCOPE_AGENT);
        if (__all(f >= need)) break;
        __builtin_amdgcn_s_sleep(1);
      }
      // one acquire round to order the subsequent h loads
      if (lane < 16)
        (void)__hip_atomic_load(&flags[lane], __ATOMIC_ACQUIRE, __HIP_MEMORY_SCOPE_AGENT);
    }

    // ---- K loop: 16 chunks of 32, depth-4 register prefetch, no barriers ----
    float4v acc[4][4];
#pragma unroll
    for (int mi = 0; mi < 4; ++mi)
#pragma unroll
      for (int ni = 0; ni < 4; ++ni) acc[mi][ni] = (float4v)0.f;

    half8 hr[4][4];                    // [ring][mi]
#pragma unroll
    for (int p = 0; p < 4; ++p)
#pragma unroll
      for (int mi = 0; mi < 4; ++mi)
        hr[p][mi] = *(const half8*)(hsrc + aoff[mi] + p * 32);
    half8 afc[4];
#pragma unroll
    for (int ni = 0; ni < 4; ++ni) afc[ni] = *(const half8*)&Bt[boff[ni]];

#pragma unroll
    for (int kc = 0; kc < 16; ++kc) {
      half8 bcur[4];
#pragma unroll
      for (int mi = 0; mi < 4; ++mi) bcur[mi] = hr[kc & 3][mi];
      if (kc < 12)
#pragma unroll
        for (int mi = 0; mi < 4; ++mi)
          hr[kc & 3][mi] = *(const half8*)(hsrc + aoff[mi] + (kc + 4) * 32);
      half8 afn[4];
      if (kc < 15)
#pragma unroll
        for (int ni = 0; ni < 4; ++ni) afn[ni] = *(const half8*)&Bt[boff[ni] + (kc + 1) * 32];
#pragma unroll
      for (int mi = 0; mi < 4; ++mi)
#pragma unroll
        for (int ni = 0; ni < 4; ++ni)
          acc[mi][ni] = __builtin_amdgcn_mfma_f32_16x16x32_f16(afc[ni], bcur[mi], acc[mi][ni], 0, 0, 0);
#pragma unroll
      for (int ni = 0; ni < 4; ++ni) afc[ni] = afn[ni];
    }

    if (isFC) {
      // ---- FC epilogue: atomicAdd into bias-initialized out ----
#pragma unroll
      for (int mi = 0; mi < 4; ++mi) {
        int b = b0 + wb0 + mi * 16 + (lane & 15);
        size_t rbase = ((size_t)b * Sd + tcur) * Vd;
#pragma unroll
        for (int ni = 0; ni < 4; ++ni) {
          int v = wn0 + ni * 16 + (lane >> 4) * 4;
#pragma unroll
          for (int r2 = 0; r2 < 4; ++r2)
            atomicAdd(&out[rbase + v + r2], acc[mi][ni][r2]);
        }
      }
      __syncthreads();                 // all waves' h reads complete
      if (tid == 0)
        __hip_atomic_fetch_add(frd, 1, __ATOMIC_RELEASE, __HIP_MEMORY_SCOPE_AGENT);
    } else {
      // ---- LSTM epilogue ----
#pragma unroll
      for (int mi = 0; mi < 4; ++mi) {
        int bl = wb0 + mi * 16 + (lane & 15);
#pragma unroll
        for (int ni = 0; ni < 4; ++ni) {
          int kl = klq + ni * 4;
          float gi = sigf(acc[mi][ni][0] + wpre[mi][ni].x);
          float gf = sigf(acc[mi][ni][1] + wpre[mi][ni].y);
          float go = sigf(acc[mi][ni][2] + wpre[mi][ni].z);
          float gg = tanhfast(acc[mi][ni][3] + wpre[mi][ni].w);
          float cn = gf * creg[mi][ni] + gi * gg;
          creg[mi][ni] = cn;
          hT[bl * 40 + kl] = (_Float16)(go * tanhfast(cn));
        }
      }
      __syncthreads();                 // hT complete + all h^it reads done
      if (tid == 0) {
        // publish "done reading h^it"
        __hip_atomic_fetch_add(lrd, 1, __ATOMIC_RELEASE, __HIP_MEMORY_SCOPE_AGENT);
        // ring safety before overwriting h^{it-2}'s slot (2-iter slack, rarely blocks)
        if (it >= 2) {
          int tgtL = 16 * (it - 1);
          while (__hip_atomic_load(lrd, __ATOMIC_RELAXED, __HIP_MEMORY_SCOPE_AGENT) < tgtL)
            __builtin_amdgcn_s_sleep(1);
        }
        if (it >= 3) {
          int tgtF = it - 2;
          while (__hip_atomic_load(frd, __ATOMIC_RELAXED, __HIP_MEMORY_SCOPE_AGENT) < tgtF)
            __builtin_amdgcn_s_sleep(1);
        }
      }
      __syncthreads();
      // coalesced h slice store
#pragma unroll
      for (int j = 0; j < 2; ++j) {
        int bl = (tid >> 2) + j * 64;
        int seg = tid & 3;
        half8 hv = *(const half8*)&hT[bl * 40 + seg * 8];
        *(half8*)(hdst + (b0 + bl) * 512 + nt * 32 + seg * 8) = hv;
      }
      __syncthreads();                 // each wave drains vmcnt before barrier
      if (tid == 0)
        __hip_atomic_store(&flags[nt], it + 1, __ATOMIC_RELEASE, __HIP_MEMORY_SCOPE_AGENT);
    }
  }
}

extern "C" void kernel_launch(void* const* d_in, const int* in_sizes, int n_in,
                              void* d_out, int out_size, void* d_ws, size_t ws_size,
                              hipStream_t stream) {
  const int* x      = (const int*)d_in[0];
  const float* WxF  = (const float*)d_in[1];
  const float* WhF  = (const float*)d_in[2];
  const float* bxF  = (const float*)d_in[3];
  const float* bhF  = (const float*)d_in[4];
  const float* WxB  = (const float*)d_in[5];
  const float* WhB  = (const float*)d_in[6];
  const float* bxB  = (const float*)d_in[7];
  const float* bhB  = (const float*)d_in[8];
  const float* Wfc  = (const float*)d_in[9];
  const float* bfc  = (const float*)d_in[10];
  float* out = (float*)d_out;

  // ws layout (float offsets):
  //   wxt   @ 0          len 524,288
  //   wh16  @ 524,288    len 1,048,576 (2,097,152 halves)
  //   wfc16 @ 1,572,864  len 65,536    (131,072 halves)
  //   cnt   @ 1,638,400  len 256 ints  (flags[128] | lrd[8] | frd[8] | pad)
  //   hring @ 1,638,656  len 786,432   (3 slots x 524,288 halves)
  float* ws = (float*)d_ws;
  float* wxt = ws;
  _Float16* wh16 = (_Float16*)(ws + 524288);
  _Float16* wfc16 = (_Float16*)(ws + 1572864);
  int* cnt = (int*)(ws + 1638400);
  _Float16* hring = (_Float16*)(ws + 1638656);

  prep_wxt<<<2048, 256, 0, stream>>>(WxF, bxF, bhF, WxB, bxB, bhB, wxt);
  prep_wh16<<<8192, 256, 0, stream>>>(WhF, WhB, wh16);
  prep_wfc16<<<512, 256, 0, stream>>>(Wfc, wfc16);
  // zero cnt(256) + h ring slot 0 (262,144 floats worth): 65,600 float4
  init_zero<<<257, 256, 0, stream>>>(ws + 1638400, 65600);
  init_out<<<16384, 256, 0, stream>>>(bfc, out);

  bilstm_persist<<<136, 256, 0, stream>>>(wxt, x, wh16, wfc16, hring, cnt, out);
}